// Round 14
// baseline (1415.798 us; speedup 1.0000x reference)
//
#include <hip/hip_runtime.h>

#define NROWS 8192
#define RPB   32       // rows per block
#define TPB   1024     // 16 waves; wave owns 2 rows x 32 feats (lane=(row,feat))
#define NBLK  256
#define SCALE 0.1714985851425088f   // 1/sqrt(34)
#define INV64 0.015625f

// wave-internal LDS handoff: drain this wave's ds_writes, block compiler motion
#define WFENCE() do { asm volatile("s_waitcnt lgkmcnt(0)" ::: "memory"); \
                      __builtin_amdgcn_sched_barrier(0); } while (0)

// workspace layout (float offsets)
#define OFF_W1   0          // 1024
#define OFF_W2   1024       // 1024
#define OFF_WIN  2048       // 102*34 = 3468
#define OFF_WFC2 5516       // 1024
#define OFF_M    6540       // 32*34 = 1088
#define OFF_B12  7628       // 32
#define OFF_BIN  7660       // 102
#define OFF_B2   7762       // 32
#define OFF_BFC2 7794       // 32
#define OFF_LNG  7826       // 32
#define OFF_LNB  7858       // 32
#define OFF_QKV0 8192
#define QKVN     (NROWS*102)          // feature-major: qkv[e][row]
#define OFF_QKV1 (OFF_QKV0 + QKVN)
#define OFF_HNEW (OFF_QKV1 + QKVN)   // ROW-major here: hnew[r][j], 32*NROWS

__global__ __launch_bounds__(256) void setup_kernel(
    const float* __restrict__ W_x2h, const float* __restrict__ b_x2h,
    const float* __restrict__ W_h2h, const float* __restrict__ b_h2h,
    const float* __restrict__ W_fc2, const float* __restrict__ b_fc2,
    const float* __restrict__ ln_g,  const float* __restrict__ ln_b,
    const float* __restrict__ W_fcsa,const float* __restrict__ b_fcsa,
    const float* __restrict__ W_in,  const float* __restrict__ b_in,
    const float* __restrict__ W_out, const float* __restrict__ b_out,
    float* __restrict__ ws)
{
  int t = blockIdx.x*blockDim.x + threadIdx.x;
  int stride = gridDim.x*blockDim.x;
  for (int i=t;i<1024;i+=stride) ws[OFF_W1+i]   = W_x2h[i];
  for (int i=t;i<1024;i+=stride) ws[OFF_W2+i]   = W_h2h[i];
  for (int i=t;i<3468;i+=stride) ws[OFF_WIN+i]  = W_in[i];
  for (int i=t;i<1024;i+=stride) ws[OFF_WFC2+i] = W_fc2[i];
  for (int i=t;i<32;i+=stride)   ws[OFF_B12+i]  = b_x2h[i] + b_h2h[i];
  for (int i=t;i<102;i+=stride)  ws[OFF_BIN+i]  = b_in[i];
  for (int i=t;i<32;i+=stride)   ws[OFF_BFC2+i] = b_fc2[i];
  for (int i=t;i<32;i+=stride)   ws[OFF_LNG+i]  = ln_g[i];
  for (int i=t;i<32;i+=stride)   ws[OFF_LNB+i]  = ln_b[i];
  // M = W_fcsa (32x34) @ W_out (34x34)
  for (int idx=t; idx<1088; idx+=stride) {
    int j = idx/34, f = idx - j*34;
    float acc = 0.f;
    for (int e=0;e<34;++e)
      acc += W_fcsa[j*34+e] * W_out[e*34+f];
    ws[OFF_M+idx] = acc;
  }
  for (int j=t;j<32;j+=stride){
    float acc = b_fcsa[j];
    for (int e=0;e<34;++e) acc += W_fcsa[j*34+e] * b_out[e];
    ws[OFF_B2+j] = acc;
  }
}

// Wave-autonomous step kernel (attacks R10/R13's barrier-convoy):
// lane = (row, feat): wave owns 2 rows x 32 features. Every post-attention
// phase (h' -> fc2 -> LN -> rnn -> qkv) reads only same-wave-produced LDS ->
// block barriers replaced by wave-internal lgkmcnt fences; LN row-sum via
// __shfl_xor (masks<32 stay in each row-half). ONE __syncthreads (weights).
// Waves slide through phases independently -> per-launch critical path is
// staging + one scattered-load phase + ~1us of wave-local compute, not the
// sum of 7 barrier-convoyed phases.
// q is staged in LDS (34 loads/row, not 306); hnew is row-major (per-lane
// register, coalesced); x / out / hnew accessed per-lane coalesced (256B/wave).
// Odd LDS strides (33/35/13) make all weight reads bank-conflict-free.
__global__ __launch_bounds__(TPB) void step_kernel(
    const float* __restrict__ ws,
    const float* __restrict__ qkvR,     // qkv of step stepB (read)
    float* __restrict__ qkvW,           // qkv of step stepA (write)
    float* __restrict__ hnewG,          // ROW-major tanh-state hnew[r][j]
    const float* __restrict__ x,
    float* __restrict__ out,
    int stepB, int stepA)
{
  __shared__ float sW1[32][33], sW2[32][33], sWfc2[32][33];
  __shared__ float sM[32][35];
  __shared__ float sWin[102][35];
  __shared__ float sB12[32], sBin[102], sB2[32], sBfc2[32], sLng[32], sLnb[32];
  __shared__ float sQ[32][35];       // staged q (34) per row
  __shared__ float sS[32][13];       // 9 scores per row
  __shared__ float sO[32][35];       // attention output (34) per row
  __shared__ float sHp[32][33];      // h' per row
  __shared__ float sPred[32][33];    // pred per row
  __shared__ float sHn[32][33];      // h_new per row
  __shared__ float sX[32][33];       // x chunk per row (steps 0..9)

  const int tid  = threadIdx.x;
  const int l    = tid & 63;
  const int j    = l & 31;                    // feature 0..31
  const int rowg = ((tid >> 6) << 1) + (l >> 5);  // row 0..31 (2 per wave)
  const int base = blockIdx.x * RPB;
  const int r2   = base + rowg;
  const int b    = base >> 12;                // batch (uniform)
  const int p    = base & 4095;
  const int gr   = p >> 6;                    // grid-row (uniform)
  const int gc0  = p & 63;                    // 0 or 32 (uniform)
  const int c    = gc0 + rowg;                // global column (per-row)
  const int br   = (gr < 1) ? 1 : ((gr > 62) ? 62 : gr);
  const int bc   = (c  < 1) ? 1 : ((c  > 62) ? 62 : c);
  const int qrow = (b<<12) + (br<<6) + bc;    // gathered center (query row)

  // ---- phase A: cooperative weight staging (the ONE barrier covers this) ----
  {
    sW1  [tid>>5][tid&31] = ws[OFF_W1  +tid];
    sW2  [tid>>5][tid&31] = ws[OFF_W2  +tid];
    sWfc2[tid>>5][tid&31] = ws[OFF_WFC2+tid];
    for (int idx=tid; idx<1088; idx+=TPB){ int jj=idx/34, e=idx-jj*34; sM[jj][e]=ws[OFF_M+idx]; }
    for (int idx=tid; idx<3468; idx+=TPB){ int e=idx/34, f=idx-e*34; sWin[e][f]=ws[OFF_WIN+idx]; }
    if (tid < 102)                sBin [tid]     = ws[OFF_BIN +tid];
    else if (tid>=128 && tid<160) sB12 [tid-128] = ws[OFF_B12 +tid-128];
    else if (tid>=160 && tid<192) sB2  [tid-160] = ws[OFF_B2  +tid-160];
    else if (tid>=192 && tid<224) sBfc2[tid-192] = ws[OFF_BFC2+tid-192];
    else if (tid>=224 && tid<256) sLng [tid-224] = ws[OFF_LNG +tid-224];
    else if (tid>=256 && tid<288) sLnb [tid-256] = ws[OFF_LNB +tid-256];
  }
  // per-lane coalesced input loads (256B per wave)
  float hprev = 0.f;
  if (stepB >= 0) hprev = hnewG[(size_t)r2*32 + j];
  if (stepA >= 0 && stepA < 10)
    sX[rowg][j] = x[((size_t)stepA*NROWS + r2)*32 + j];

  // ---- attention front-end (global-latency phase, wave-local LDS) ----
  if (stepB >= 0) {
    // stage q for own row: 34 loads/row (not 306)
    sQ[rowg][j] = qkvR[(size_t)j*NROWS + qrow];
    if (j < 2) sQ[rowg][32+j] = qkvR[(size_t)(32+j)*NROWS + qrow];
    WFENCE();
    if (j < 9) {                               // scores, m = j
      const int dr = j/3 - 1, dc = j - (j/3)*3 - 1;
      const int krow = (b<<12) + ((br+dr)<<6) + (bc+dc);
      float acc = 0.f;
      #pragma unroll
      for (int e=0;e<34;++e)
        acc += sQ[rowg][e] * qkvR[(size_t)(34+e)*NROWS + krow];
      sS[rowg][j] = acc * SCALE;
    }
    WFENCE();
    {                                          // softmax (redundant) + o
      float sc[9]; float mx = -1e30f;
      #pragma unroll
      for (int m=0;m<9;++m){ sc[m]=sS[rowg][m]; mx=fmaxf(mx,sc[m]); }
      float sum=0.f;
      #pragma unroll
      for (int m=0;m<9;++m){ sc[m]=__expf(sc[m]-mx); sum+=sc[m]; }
      float inv = 1.f/sum;
      float o0=0.f, o1=0.f;
      const bool x2 = (j < 2);
      #pragma unroll
      for (int m=0;m<9;++m){
        int dr = m/3 - 1, dc = m - (m/3)*3 - 1;
        int krow = (b<<12) + ((br+dr)<<6) + (bc+dc);
        float wm = sc[m]*inv;
        o0 += wm * qkvR[(size_t)(68+j)*NROWS + krow];
        if (x2) o1 += wm * qkvR[(size_t)(100+j)*NROWS + krow];
      }
      sO[rowg][j] = o0;
      if (x2) sO[rowg][32+j] = o1;
    }
  }
  __syncthreads();   // weights ready for everyone (single block barrier)

  // ---- wave-local back-end: h' -> fc2 -> LN -> out ----
  float hp, pred = 0.f;
  if (stepB >= 0) {
    float a = hprev + sB2[j];
    #pragma unroll
    for (int e=0;e<34;++e) a += sO[rowg][e] * sM[j][e];   // sO broadcast, sM cf
    hp = a;
  } else {
    hp = 0.f;                                  // step 0: h' = 0
  }
  sHp[rowg][j] = hp;
  WFENCE();
  if (stepB >= 0) {
    float g = sBfc2[j];
    #pragma unroll
    for (int i=0;i<32;++i) g += sHp[rowg][i] * sWfc2[j][i];
    // layernorm across the row's 32 lanes (xor masks <32 stay in-half)
    float mu = g;
    #pragma unroll
    for (int k=1;k<32;k<<=1) mu += __shfl_xor(mu, k, 64);
    mu *= 0.03125f;
    float d = g - mu;
    float var = d*d;
    #pragma unroll
    for (int k=1;k<32;k<<=1) var += __shfl_xor(var, k, 64);
    var *= 0.03125f;
    float rs = rsqrtf(var + 1e-5f);
    pred = d*rs*sLng[j] + sLnb[j];
    out[((size_t)stepB*NROWS + r2)*32 + j] = pred;        // coalesced 256B/wave
    sPred[rowg][j] = pred;
  }

  // ---- wave-local rnn + qkv ----
  if (stepA >= 0) {
    WFENCE();                                  // sPred/sHp visible to own wave
    float a = sB12[j];
    if (stepA < 10) {
      #pragma unroll
      for (int i=0;i<32;++i)
        a += sX[rowg][i]*sW1[j][i] + sHp[rowg][i]*sW2[j][i];
    } else {
      #pragma unroll
      for (int i=0;i<32;++i)
        a += sPred[rowg][i]*sW1[j][i] + sHp[rowg][i]*sW2[j][i];
    }
    float hn = tanhf(a);
    sHn[rowg][j] = hn;
    hnewG[(size_t)r2*32 + j] = hn;             // row-major, coalesced
    WFENCE();
    const float pl0 = gr*INV64, pl1 = c*INV64;
    #pragma unroll
    for (int k=0;k<4;++k){
      int e = j + 32*k;
      if (e < 102) {
        float acc = sBin[e];
        #pragma unroll
        for (int f=0;f<32;++f) acc += sHn[rowg][f]*sWin[e][f];  // cf strides
        acc += pl0*sWin[e][32] + pl1*sWin[e][33];
        qkvW[(size_t)e*NROWS + r2] = acc;      // feature-major (as consumed)
      }
    }
  }
}

extern "C" void kernel_launch(void* const* d_in, const int* in_sizes, int n_in,
                              void* d_out, int out_size, void* d_ws, size_t ws_size,
                              hipStream_t stream) {
  const float* x     = (const float*)d_in[0];
  const float* W_x2h = (const float*)d_in[1];
  const float* b_x2h = (const float*)d_in[2];
  const float* W_h2h = (const float*)d_in[3];
  const float* b_h2h = (const float*)d_in[4];
  const float* W_fc2 = (const float*)d_in[5];
  const float* b_fc2 = (const float*)d_in[6];
  const float* ln_g  = (const float*)d_in[7];
  const float* ln_b  = (const float*)d_in[8];
  const float* W_fcsa= (const float*)d_in[9];
  const float* b_fcsa= (const float*)d_in[10];
  const float* W_in  = (const float*)d_in[11];
  const float* b_in  = (const float*)d_in[12];
  const float* W_out = (const float*)d_in[13];
  const float* b_out = (const float*)d_in[14];
  float* ws = (float*)d_ws;
  float* out = (float*)d_out;

  setup_kernel<<<8, 256, 0, stream>>>(W_x2h,b_x2h,W_h2h,b_h2h,W_fc2,b_fc2,ln_g,ln_b,
                                      W_fcsa,b_fcsa,W_in,b_in,W_out,b_out, ws);
  for (int i=0;i<60;++i){
    int stepB = i-1;
    int stepA = (i<=58)? i : -1;
    const float* qR = ws + OFF_QKV0 + (size_t)((i+1)&1)*QKVN;  // qkv of step i-1
    float*       qW = ws + OFF_QKV0 + (size_t)(i&1)*QKVN;      // qkv of step i
    step_kernel<<<NBLK, TPB, 0, stream>>>(ws, qR, qW, ws+OFF_HNEW, x, out, stepB, stepA);
  }
}

// Round 15
// 1160.712 us; speedup vs baseline: 1.2198x; 1.2198x over previous
//
#include <hip/hip_runtime.h>

#define NROWS 8192
#define RPB   32       // rows per block
#define TPB   1024     // 16 waves; slot = tid>>5 (0..31), row lane = tid&31
#define NBLK  256      // 1 block/CU
#define SCALE 0.1714985851425088f   // 1/sqrt(34)
#define INV64 0.015625f

// workspace layout (float offsets)
#define OFF_W1   0          // 1024
#define OFF_W2   1024       // 1024
#define OFF_WIN  2048       // 102*34 = 3468
#define OFF_WFC2 5516       // 1024
#define OFF_M    6540       // 32*34 = 1088
#define OFF_B12  7628       // 32
#define OFF_BIN  7660       // 102
#define OFF_B2   7762       // 32
#define OFF_BFC2 7794       // 32
#define OFF_LNG  7826       // 32
#define OFF_LNB  7858       // 32
#define OFF_QKV0 8192
#define QKVN     (NROWS*102)          // feature-major: qkv[e][row]
#define OFF_QKV1 (OFF_QKV0 + QKVN)
#define OFF_HNEW (OFF_QKV1 + QKVN)   // feature-major: hnew[j][row], 32*NROWS

__global__ __launch_bounds__(256) void setup_kernel(
    const float* __restrict__ W_x2h, const float* __restrict__ b_x2h,
    const float* __restrict__ W_h2h, const float* __restrict__ b_h2h,
    const float* __restrict__ W_fc2, const float* __restrict__ b_fc2,
    const float* __restrict__ ln_g,  const float* __restrict__ ln_b,
    const float* __restrict__ W_fcsa,const float* __restrict__ b_fcsa,
    const float* __restrict__ W_in,  const float* __restrict__ b_in,
    const float* __restrict__ W_out, const float* __restrict__ b_out,
    float* __restrict__ ws)
{
  int t = blockIdx.x*blockDim.x + threadIdx.x;
  int stride = gridDim.x*blockDim.x;
  for (int i=t;i<1024;i+=stride) ws[OFF_W1+i]   = W_x2h[i];
  for (int i=t;i<1024;i+=stride) ws[OFF_W2+i]   = W_h2h[i];
  for (int i=t;i<3468;i+=stride) ws[OFF_WIN+i]  = W_in[i];
  for (int i=t;i<1024;i+=stride) ws[OFF_WFC2+i] = W_fc2[i];
  for (int i=t;i<32;i+=stride)   ws[OFF_B12+i]  = b_x2h[i] + b_h2h[i];
  for (int i=t;i<102;i+=stride)  ws[OFF_BIN+i]  = b_in[i];
  for (int i=t;i<32;i+=stride)   ws[OFF_BFC2+i] = b_fc2[i];
  for (int i=t;i<32;i+=stride)   ws[OFF_LNG+i]  = ln_g[i];
  for (int i=t;i<32;i+=stride)   ws[OFF_LNB+i]  = ln_b[i];
  // M = W_fcsa (32x34) @ W_out (34x34)
  for (int idx=t; idx<1088; idx+=stride) {
    int j = idx/34, f = idx - j*34;
    float acc = 0.f;
    for (int e=0;e<34;++e)
      acc += W_fcsa[j*34+e] * W_out[e*34+f];
    ws[OFF_M+idx] = acc;
  }
  for (int j=t;j<32;j+=stride){
    float acc = b_fcsa[j];
    for (int e=0;e<34;++e) acc += W_fcsa[j*34+e] * b_out[e];
    ws[OFF_B2+j] = acc;
  }
}

// R10 structure (best-known: 962us) + bulk-staged attention window.
// slot = tid>>5 (feature/work slot), lanes = rows (coalesced global access in
// EVERY phase -- R14's lesson). Change vs R10: instead of ~29K scattered,
// partially-redundant global lane-loads in the scores/o phases (k re-read per
// neighbor window, v re-read per feature slot, chained in 9/34-iter loops
// against cross-XCD L3 latency), phase A bulk-stages the 3x34-cell qkv
// neighbor window (all 102 feats, 42KB LDS, 10.4K coalesced loads issued in
// one burst). Scores/softmax/o become short LDS-only phases. Odd strides
// (103/35/33/13) keep every LDS access bank-conflict-free.
__global__ __launch_bounds__(TPB) void step_kernel(
    const float* __restrict__ ws,
    const float* __restrict__ qkvR,     // qkv of step stepB (read)
    float* __restrict__ qkvW,           // qkv of step stepA (write)
    float* __restrict__ hnewG,          // feature-major tanh-state
    const float* __restrict__ x,
    float* __restrict__ out,
    int stepB, int stepA)
{
  __shared__ float sW1[32][33], sW2[32][33], sWfc2[32][33];
  __shared__ float sM[32][35];
  __shared__ float sWin[102][35];
  __shared__ float sB12[32], sBin[102], sB2[32], sBfc2[32], sLng[32], sLnb[32];
  __shared__ float sKV[3][34][103];  // qkv window: [grid-row][col][feat]
  __shared__ float sS[RPB][13];      // 9 scores
  __shared__ float sO[RPB][35];      // attention output (34)
  __shared__ float sHprev[RPB][33];  // prev h_new (staged in A)
  __shared__ float sHp[RPB][33];     // h'
  __shared__ float sG[RPB][33];      // pre-LN fc2 output
  __shared__ float sPred[RPB][33];   // pred
  __shared__ float sHn[RPB][33];     // h_new (tanh output)
  __shared__ float sX[RPB][33];      // x chunk (steps 0..9)

  const int tid  = threadIdx.x;
  const int lr2  = tid & 31;         // row within block
  const int slot = tid >> 5;         // work slot 0..31
  const int base = blockIdx.x * RPB;
  const int r2   = base + lr2;
  const int b    = base >> 12;       // batch (uniform)
  const int p    = base & 4095;
  const int gr   = p >> 6;           // grid-row (uniform)
  const int gc0  = p & 63;           // 0 or 32 (uniform)
  const int c    = gc0 + lr2;        // global column (per-lane)
  const int br   = (gr < 1) ? 1 : ((gr > 62) ? 62 : gr);   // uniform
  const int bc   = (c  < 1) ? 1 : ((c  > 62) ? 62 : c);    // per-lane
  const int ccq  = bc - gc0 + 1;     // own center's col in window (0..33)

  // ---- phase A: stage weights/biases, qkv window, hnew, x ----
  {
    sW1  [tid>>5][tid&31] = ws[OFF_W1  +tid];
    sW2  [tid>>5][tid&31] = ws[OFF_W2  +tid];
    sWfc2[tid>>5][tid&31] = ws[OFF_WFC2+tid];
    for (int idx=tid; idx<1088; idx+=TPB){ int j=idx/34, e=idx-j*34; sM[j][e]=ws[OFF_M+idx]; }
    for (int idx=tid; idx<3468; idx+=TPB){ int e=idx/34, f=idx-e*34; sWin[e][f]=ws[OFF_WIN+idx]; }
    if (tid < 102)                    sBin [tid]     = ws[OFF_BIN +tid];
    else if (tid>=128 && tid<160)     sB12 [tid-128] = ws[OFF_B12 +tid-128];
    else if (tid>=160 && tid<192)     sB2  [tid-160] = ws[OFF_B2  +tid-160];
    else if (tid>=192 && tid<224)     sBfc2[tid-192] = ws[OFF_BFC2+tid-192];
    else if (tid>=224 && tid<256)     sLng [tid-224] = ws[OFF_LNG +tid-224];
    else if (tid>=256 && tid<288)     sLnb [tid-256] = ws[OFF_LNB +tid-256];
  }
  if (stepA >= 0 && stepA < 10) {
    size_t xbase = ((size_t)stepA*NROWS + base)*32;
    sX[tid>>5][tid&31] = x[xbase + tid];              // 1024 floats, coalesced
  }
  if (stepB >= 0) {
    // prev h_new (feature-major global, coalesced) -> sHprev[row][feat]
    {
      int j = tid >> 5, r = tid & 31;
      sHprev[r][j] = hnewG[(size_t)j*NROWS + base + r];
    }
    // qkv window: 102 feats x (3 grid-rows x 34 cols), coalesced 34-col runs
    for (int idx = tid; idx < 10404; idx += TPB) {
      int e    = idx / 102;
      int cell = idx - e*102;
      int rr   = cell / 34, cc = cell - rr*34;
      int gcol = gc0 - 1 + cc;
      gcol = (gcol < 0) ? 0 : ((gcol > 63) ? 63 : gcol);
      int flat = (b<<12) + ((br-1+rr)<<6) + gcol;
      sKV[rr][cc][e] = qkvR[(size_t)e*NROWS + flat];
    }
  } else {
    if (slot < 32) sHp[lr2][slot] = 0.f;              // step 0: h' = 0
  }
  __syncthreads();

  if (stepB >= 0) {
    // ---- B: scores from LDS (slots 0..8, m = slot) ----
    if (slot < 9) {
      const int dr = slot/3 - 1, dc = slot - (slot/3)*3 - 1;
      const int rrk = 1 + dr, cck = ccq + dc;
      float acc = 0.f;
      #pragma unroll
      for (int e=0;e<34;++e)
        acc += sKV[1][ccq][e] * sKV[rrk][cck][34+e];
      sS[lr2][slot] = acc * SCALE;
    }
    __syncthreads();
    // ---- C: softmax (redundant per slot) + o from LDS ----
    {
      float sc[9]; float mx = -1e30f;
      #pragma unroll
      for (int m=0;m<9;++m){ sc[m]=sS[lr2][m]; mx=fmaxf(mx,sc[m]); }
      float sum=0.f;
      #pragma unroll
      for (int m=0;m<9;++m){ sc[m]=__expf(sc[m]-mx); sum+=sc[m]; }
      float inv = 1.f/sum;
      float o0=0.f, o1=0.f;
      const bool e2ok = (slot < 2);
      #pragma unroll
      for (int m=0;m<9;++m){
        int dr = m/3 - 1, dc = m - (m/3)*3 - 1;
        int rrk = 1 + dr, cck = ccq + dc;
        float wm = sc[m]*inv;
        o0 += wm * sKV[rrk][cck][68+slot];
        if (e2ok) o1 += wm * sKV[rrk][cck][100+slot];
      }
      sO[lr2][slot] = o0;
      if (e2ok) sO[lr2][32+slot] = o1;
    }
    __syncthreads();
    // ---- D: h' = h_prev + o @ M^T + b2 : slot -> j ----
    {
      float a = sB2[slot] + sHprev[lr2][slot];
      #pragma unroll
      for (int e=0;e<34;++e) a += sO[lr2][e] * sM[slot][e];
      sHp[lr2][slot] = a;
    }
    __syncthreads();
    // ---- E: g = h' @ Wfc2^T + b ----
    {
      float g = sBfc2[slot];
      #pragma unroll
      for (int i=0;i<32;++i) g += sHp[lr2][i] * sWfc2[slot][i];
      sG[lr2][slot] = g;
    }
    __syncthreads();
    // ---- F: layernorm -> sPred + out ----
    {
      float mu=0.f;
      #pragma unroll
      for (int i=0;i<32;++i) mu += sG[lr2][i];
      mu *= 0.03125f;
      float var=0.f;
      #pragma unroll
      for (int i=0;i<32;++i){ float d=sG[lr2][i]-mu; var += d*d; }
      var *= 0.03125f;
      float rs = rsqrtf(var + 1e-5f);
      sPred[lr2][slot] = (sG[lr2][slot]-mu)*rs*sLng[slot] + sLnb[slot];
    }
    __syncthreads();
    {
      size_t obase = ((size_t)stepB*NROWS + base)*32;
      out[obase + tid] = sPred[tid>>5][tid&31];       // coalesced
    }
  }

  if (stepA >= 0) {
    // ---- G: h_new = tanh(inp@W1^T + h'@W2^T + b) : slot -> j ----
    {
      float a = sB12[slot];
      if (stepA < 10) {
        #pragma unroll
        for (int i=0;i<32;++i)
          a += sX[lr2][i]*sW1[slot][i] + sHp[lr2][i]*sW2[slot][i];
      } else {
        #pragma unroll
        for (int i=0;i<32;++i)
          a += sPred[lr2][i]*sW1[slot][i] + sHp[lr2][i]*sW2[slot][i];
      }
      float t0 = tanhf(a);
      sHn[lr2][slot] = t0;
      hnewG[(size_t)slot*NROWS + r2] = t0;            // coalesced 128B/slot
    }
    __syncthreads();
    // ---- H: qkv = [h_new, pl] @ W_in^T + b_in : slot -> e = slot + 32k ----
    float hn[32];
    #pragma unroll
    for (int f=0;f<32;++f) hn[f]=sHn[lr2][f];
    const float pl0 = gr*INV64, pl1 = c*INV64;
    #pragma unroll
    for (int k=0;k<4;++k){
      int e = slot + 32*k;
      if (e < 102) {
        float acc = sBin[e];
        #pragma unroll
        for (int f=0;f<32;++f) acc += hn[f]*sWin[e][f];
        acc += pl0*sWin[e][32] + pl1*sWin[e][33];
        qkvW[(size_t)e*NROWS + r2] = acc;             // coalesced 128B/e
      }
    }
  }
}

extern "C" void kernel_launch(void* const* d_in, const int* in_sizes, int n_in,
                              void* d_out, int out_size, void* d_ws, size_t ws_size,
                              hipStream_t stream) {
  const float* x     = (const float*)d_in[0];
  const float* W_x2h = (const float*)d_in[1];
  const float* b_x2h = (const float*)d_in[2];
  const float* W_h2h = (const float*)d_in[3];
  const float* b_h2h = (const float*)d_in[4];
  const float* W_fc2 = (const float*)d_in[5];
  const float* b_fc2 = (const float*)d_in[6];
  const float* ln_g  = (const float*)d_in[7];
  const float* ln_b  = (const float*)d_in[8];
  const float* W_fcsa= (const float*)d_in[9];
  const float* b_fcsa= (const float*)d_in[10];
  const float* W_in  = (const float*)d_in[11];
  const float* b_in  = (const float*)d_in[12];
  const float* W_out = (const float*)d_in[13];
  const float* b_out = (const float*)d_in[14];
  float* ws = (float*)d_ws;
  float* out = (float*)d_out;

  setup_kernel<<<8, 256, 0, stream>>>(W_x2h,b_x2h,W_h2h,b_h2h,W_fc2,b_fc2,ln_g,ln_b,
                                      W_fcsa,b_fcsa,W_in,b_in,W_out,b_out, ws);
  for (int i=0;i<60;++i){
    int stepB = i-1;
    int stepA = (i<=58)? i : -1;
    const float* qR = ws + OFF_QKV0 + (size_t)((i+1)&1)*QKVN;  // qkv of step i-1
    float*       qW = ws + OFF_QKV0 + (size_t)(i&1)*QKVN;      // qkv of step i
    step_kernel<<<NBLK, TPB, 0, stream>>>(ws, qR, qW, ws+OFF_HNEW, x, out, stepB, stepA);
  }
}

// Round 16
// 998.501 us; speedup vs baseline: 1.4179x; 1.1625x over previous
//
#include <hip/hip_runtime.h>

#define NROWS 8192
#define RPB   32       // rows per block
#define TPB   1024     // 16 waves; slot = tid>>5 (0..31), row lane = tid&31
#define NBLK  256      // 1 block/CU
#define SCALE 0.1714985851425088f   // 1/sqrt(34)
#define INV64 0.015625f

// wave-internal LDS handoff: drain this wave's ds ops, pin compiler motion
#define WFENCE() do { asm volatile("s_waitcnt lgkmcnt(0)" ::: "memory"); \
                      __builtin_amdgcn_sched_barrier(0); } while (0)

// workspace layout (float offsets)
#define OFF_W1   0          // 1024
#define OFF_W2   1024       // 1024
#define OFF_WIN  2048       // 102*34 = 3468
#define OFF_WFC2 5516       // 1024
#define OFF_M    6540       // 32*34 = 1088
#define OFF_B12  7628       // 32
#define OFF_BIN  7660       // 102
#define OFF_B2   7762       // 32
#define OFF_BFC2 7794       // 32
#define OFF_LNG  7826       // 32
#define OFF_LNB  7858       // 32
#define OFF_QKV0 8192
#define QKVN     (NROWS*102)          // feature-major: qkv[e][row]
#define OFF_QKV1 (OFF_QKV0 + QKVN)
#define OFF_HNEW (OFF_QKV1 + QKVN)   // feature-major: hnew[j][row], 32*NROWS

__global__ __launch_bounds__(256) void setup_kernel(
    const float* __restrict__ W_x2h, const float* __restrict__ b_x2h,
    const float* __restrict__ W_h2h, const float* __restrict__ b_h2h,
    const float* __restrict__ W_fc2, const float* __restrict__ b_fc2,
    const float* __restrict__ ln_g,  const float* __restrict__ ln_b,
    const float* __restrict__ W_fcsa,const float* __restrict__ b_fcsa,
    const float* __restrict__ W_in,  const float* __restrict__ b_in,
    const float* __restrict__ W_out, const float* __restrict__ b_out,
    float* __restrict__ ws)
{
  int t = blockIdx.x*blockDim.x + threadIdx.x;
  int stride = gridDim.x*blockDim.x;
  for (int i=t;i<1024;i+=stride) ws[OFF_W1+i]   = W_x2h[i];
  for (int i=t;i<1024;i+=stride) ws[OFF_W2+i]   = W_h2h[i];
  for (int i=t;i<3468;i+=stride) ws[OFF_WIN+i]  = W_in[i];
  for (int i=t;i<1024;i+=stride) ws[OFF_WFC2+i] = W_fc2[i];
  for (int i=t;i<32;i+=stride)   ws[OFF_B12+i]  = b_x2h[i] + b_h2h[i];
  for (int i=t;i<102;i+=stride)  ws[OFF_BIN+i]  = b_in[i];
  for (int i=t;i<32;i+=stride)   ws[OFF_BFC2+i] = b_fc2[i];
  for (int i=t;i<32;i+=stride)   ws[OFF_LNG+i]  = ln_g[i];
  for (int i=t;i<32;i+=stride)   ws[OFF_LNB+i]  = ln_b[i];
  // M = W_fcsa (32x34) @ W_out (34x34)
  for (int idx=t; idx<1088; idx+=stride) {
    int j = idx/34, f = idx - j*34;
    float acc = 0.f;
    for (int e=0;e<34;++e)
      acc += W_fcsa[j*34+e] * W_out[e*34+f];
    ws[OFF_M+idx] = acc;
  }
  for (int j=t;j<32;j+=stride){
    float acc = b_fcsa[j];
    for (int e=0;e<34;++e) acc += W_fcsa[j*34+e] * b_out[e];
    ws[OFF_B2+j] = acc;
  }
}

// R10 (best-known 962us) with the post-attention chain de-barriered:
// phases A-C keep R10's proven mapping (slot=tid>>5, lanes=rows: all global
// access coalesced). Phases D(h')->E(fc2)->F(LN)->out — whose dataflow is
// per-row only — are re-mapped to lane=(row,feat) (wave owns 2 rows x 32
// feats) and run as ONE wave-local region: own-wave LDS handoff via
// lgkmcnt fences, LN row-reduce via __shfl_xor masks<32 (stay in each
// 32-lane row-half; correctness of this pattern validated in R14). Barriers
// per step: 7 -> 4. sM stride 36->35 so the lane-varying sM[j][e] read is
// bank-conflict-free ((3j+e)%32 bijective); out-write stays 256B/wave.
__global__ __launch_bounds__(TPB) void step_kernel(
    const float* __restrict__ ws,
    const float* __restrict__ qkvR,     // qkv of step stepB (read)
    float* __restrict__ qkvW,           // qkv of step stepA (write)
    float* __restrict__ hnewG,          // feature-major tanh-state
    const float* __restrict__ x,
    float* __restrict__ out,
    int stepB, int stepA)
{
  __shared__ float sW1[32][33], sW2[32][33], sWfc2[32][33];
  __shared__ float sM[32][35];       // 35: odd stride (lane-varying j reads)
  __shared__ float sWin[102][36];
  __shared__ float sB12[32], sBin[102], sB2[32], sBfc2[32], sLng[32], sLnb[32];
  __shared__ float sS[RPB][13];      // 9 scores (odd stride: conflict-free)
  __shared__ float sO[RPB][35];      // attention output (34)
  __shared__ float sHprev[RPB][33];  // prestaged prev h_new
  __shared__ float sHp[RPB][33];     // h'
  __shared__ float sPred[RPB][33];   // pred (next-step input)
  __shared__ float sHn[RPB][33];     // h_new (tanh output)
  __shared__ float sX[RPB][33];      // staged x chunk (steps 0..9)

  const int tid  = threadIdx.x;
  const int lr2  = tid & 31;         // row within block (slot-map phases)
  const int slot = tid >> 5;         // work slot 0..31
  const int l    = tid & 63;
  const int j2   = l & 31;                       // feature (wave-local phases)
  const int rowg = ((tid >> 6) << 1) + (l >> 5); // row 0..31 (2 per wave)
  const int base = blockIdx.x * RPB;
  const int r2   = base + lr2;
  const int b    = base >> 12;       // batch (uniform)
  const int p    = base & 4095;
  const int gr   = p >> 6;           // grid-row (uniform)
  const int gc0  = p & 63;           // 0 or 32 (uniform)
  const int c    = gc0 + lr2;        // global column (per-lane)
  const int br   = (gr < 1) ? 1 : ((gr > 62) ? 62 : gr);
  const int bc   = (c  < 1) ? 1 : ((c  > 62) ? 62 : c);

  // ---- phase A (no deps, fully concurrent): stage weights/biases + x,
  //      prestage hnew (slots 16..31), scores (slots 0..8) ----
  {
    sW1  [tid>>5][tid&31] = ws[OFF_W1  +tid];
    sW2  [tid>>5][tid&31] = ws[OFF_W2  +tid];
    sWfc2[tid>>5][tid&31] = ws[OFF_WFC2+tid];
    for (int idx=tid; idx<1088; idx+=TPB){ int j=idx/34, e=idx-j*34; sM[j][e]=ws[OFF_M+idx]; }
    for (int idx=tid; idx<3468; idx+=TPB){ int e=idx/34, f=idx-e*34; sWin[e][f]=ws[OFF_WIN+idx]; }
    if (tid < 102)                    sBin [tid]     = ws[OFF_BIN +tid];
    else if (tid>=128 && tid<160)     sB12 [tid-128] = ws[OFF_B12 +tid-128];
    else if (tid>=160 && tid<192)     sB2  [tid-160] = ws[OFF_B2  +tid-160];
    else if (tid>=192 && tid<224)     sBfc2[tid-192] = ws[OFF_BFC2+tid-192];
    else if (tid>=224 && tid<256)     sLng [tid-224] = ws[OFF_LNG +tid-224];
    else if (tid>=256 && tid<288)     sLnb [tid-256] = ws[OFF_LNB +tid-256];
  }
  if (stepA >= 0 && stepA < 10) {
    size_t xbase = ((size_t)stepA*NROWS + base)*32;
    sX[tid>>5][tid&31] = x[xbase + tid];           // 1024 floats, coalesced
  }
  if (stepB >= 0) {
    if (slot >= 16) {                               // prestage hnew -> sHprev
      const int j0 = (slot-16)*2;
      sHprev[lr2][j0]   = hnewG[(size_t)j0    *NROWS + r2];
      sHprev[lr2][j0+1] = hnewG[(size_t)(j0+1)*NROWS + r2];
    } else if (slot < 9) {                          // scores, m = slot
      const int m  = slot;
      const int dr = m/3 - 1, dc = m - (m/3)*3 - 1;
      const int qrow = (b<<12) + (br<<6) + bc;
      const int nr_  = (b<<12) + ((br+dr)<<6) + (bc+dc);
      float acc = 0.f;
      #pragma unroll
      for (int e=0;e<34;++e)
        acc += qkvR[(size_t)e*NROWS + qrow] * qkvR[(size_t)(34+e)*NROWS + nr_];
      sS[lr2][m] = acc * SCALE;
    }
  } else {
    sHp[lr2][slot] = 0.f;                           // step 0: h' = 0
  }
  __syncthreads();                                  // barrier 1

  if (stepB >= 0) {
    // ---- C: softmax (redundant per slot) + o feature(s) ----
    {
      float sc[9]; float mx = -1e30f;
      #pragma unroll
      for (int m=0;m<9;++m){ sc[m]=sS[lr2][m]; mx=fmaxf(mx,sc[m]); }
      float sum=0.f;
      #pragma unroll
      for (int m=0;m<9;++m){ sc[m]=__expf(sc[m]-mx); sum+=sc[m]; }
      float inv = 1.f/sum;
      float o0=0.f, o1=0.f;
      const bool e2ok = (slot < 2);
      #pragma unroll
      for (int m=0;m<9;++m){
        int dr = m/3 - 1, dc = m - (m/3)*3 - 1;
        int nr_ = (b<<12) + ((br+dr)<<6) + (bc+dc);
        float wm = sc[m]*inv;
        o0 += wm * qkvR[(size_t)(68+slot)*NROWS + nr_];
        if (e2ok) o1 += wm * qkvR[(size_t)(100+slot)*NROWS + nr_];
      }
      sO[lr2][slot] = o0;
      if (e2ok) sO[lr2][32+slot] = o1;
    }
    __syncthreads();                                // barrier 2

    // ---- D-F + out: wave-local (lane=(row,feat), 2 rows/wave) ----
    {
      // D: h' = h_prev + o @ M^T + b2    (sO/sHprev broadcast reads; sM cf)
      float hp = sHprev[rowg][j2] + sB2[j2];
      #pragma unroll
      for (int e=0;e<34;++e) hp += sO[rowg][e] * sM[j2][e];
      sHp[rowg][j2] = hp;
      WFENCE();                      // own-wave handoff (pattern: R14, passed)
      // E: g = h' @ Wfc2^T + b          (sHp broadcast; sWfc2 (j+i)%32 cf)
      float g = sBfc2[j2];
      #pragma unroll
      for (int i=0;i<32;++i) g += sHp[rowg][i] * sWfc2[j2][i];
      // F: layernorm across the row's 32 lanes (xor masks<32 stay in-half)
      float mu = g;
      #pragma unroll
      for (int k=1;k<32;k<<=1) mu += __shfl_xor(mu, k, 64);
      mu *= 0.03125f;
      float d = g - mu;
      float var = d*d;
      #pragma unroll
      for (int k=1;k<32;k<<=1) var += __shfl_xor(var, k, 64);
      var *= 0.03125f;
      float rs = rsqrtf(var + 1e-5f);
      float pred = d*rs*sLng[j2] + sLnb[j2];
      sPred[rowg][j2] = pred;
      // out from register: 256B contiguous per wave
      out[((size_t)stepB*NROWS + base + rowg)*32 + j2] = pred;
    }
    __syncthreads();                                // barrier 3 (remap for G)
  }

  if (stepA >= 0) {
    // ---- G: h_new = tanh(inp@W1^T + h'@W2^T + b) : slot map ----
    {
      float a = sB12[slot];
      if (stepA < 10) {
        #pragma unroll
        for (int i=0;i<32;++i)
          a += sX[lr2][i]*sW1[slot][i] + sHp[lr2][i]*sW2[slot][i];
      } else {
        #pragma unroll
        for (int i=0;i<32;++i)
          a += sPred[lr2][i]*sW1[slot][i] + sHp[lr2][i]*sW2[slot][i];
      }
      float t0 = tanhf(a);
      sHn[lr2][slot] = t0;
      hnewG[(size_t)slot*NROWS + r2] = t0;          // coalesced 128B/slot
    }
    __syncthreads();                                // barrier 4
    // ---- H: qkv = [h_new, pl] @ W_in^T + b_in : slot -> e = slot + 32k ----
    float hn[32];
    #pragma unroll
    for (int f=0;f<32;++f) hn[f]=sHn[lr2][f];
    const float pl0 = gr*INV64, pl1 = c*INV64;
    #pragma unroll
    for (int k=0;k<4;++k){
      int e = slot + 32*k;
      if (e < 102) {
        float acc = sBin[e];
        #pragma unroll
        for (int f=0;f<32;++f) acc += hn[f]*sWin[e][f];
        acc += pl0*sWin[e][32] + pl1*sWin[e][33];
        qkvW[(size_t)e*NROWS + r2] = acc;           // coalesced 128B/e
      }
    }
  }
}

extern "C" void kernel_launch(void* const* d_in, const int* in_sizes, int n_in,
                              void* d_out, int out_size, void* d_ws, size_t ws_size,
                              hipStream_t stream) {
  const float* x     = (const float*)d_in[0];
  const float* W_x2h = (const float*)d_in[1];
  const float* b_x2h = (const float*)d_in[2];
  const float* W_h2h = (const float*)d_in[3];
  const float* b_h2h = (const float*)d_in[4];
  const float* W_fc2 = (const float*)d_in[5];
  const float* b_fc2 = (const float*)d_in[6];
  const float* ln_g  = (const float*)d_in[7];
  const float* ln_b  = (const float*)d_in[8];
  const float* W_fcsa= (const float*)d_in[9];
  const float* b_fcsa= (const float*)d_in[10];
  const float* W_in  = (const float*)d_in[11];
  const float* b_in  = (const float*)d_in[12];
  const float* W_out = (const float*)d_in[13];
  const float* b_out = (const float*)d_in[14];
  float* ws = (float*)d_ws;
  float* out = (float*)d_out;

  setup_kernel<<<8, 256, 0, stream>>>(W_x2h,b_x2h,W_h2h,b_h2h,W_fc2,b_fc2,ln_g,ln_b,
                                      W_fcsa,b_fcsa,W_in,b_in,W_out,b_out, ws);
  for (int i=0;i<60;++i){
    int stepB = i-1;
    int stepA = (i<=58)? i : -1;
    const float* qR = ws + OFF_QKV0 + (size_t)((i+1)&1)*QKVN;  // qkv of step i-1
    float*       qW = ws + OFF_QKV0 + (size_t)(i&1)*QKVN;      // qkv of step i
    step_kernel<<<NBLK, TPB, 0, stream>>>(ws, qR, qW, ws+OFF_HNEW, x, out, stepB, stepA);
  }
}

// Round 17
// 941.767 us; speedup vs baseline: 1.5033x; 1.0602x over previous
//
#include <hip/hip_runtime.h>

#define NROWS 8192
#define RPB   32       // rows per block
#define TPB   1024     // 16 waves; slot = tid>>5 (0..31), row lane = tid&31
#define NBLK  256      // 1 block/CU
#define SCALE 0.1714985851425088f   // 1/sqrt(34)
#define INV64 0.015625f

// workspace layout (float offsets)
#define OFF_W1   0          // 1024
#define OFF_W2   1024       // 1024
#define OFF_WIN  2048       // 102*34 = 3468
#define OFF_WFC2 5516       // 1024
#define OFF_M    6540       // 32*34 = 1088
#define OFF_B12  7628       // 32
#define OFF_BIN  7660       // 102
#define OFF_B2   7762       // 32
#define OFF_BFC2 7794       // 32
#define OFF_LNG  7826       // 32
#define OFF_LNB  7858       // 32
#define OFF_QKV0 8192
#define QKVN     (NROWS*102)          // feature-major: qkv[e][row]
#define OFF_QKV1 (OFF_QKV0 + QKVN)
#define OFF_HNEW (OFF_QKV1 + QKVN)   // feature-major: hnew[j][row], 32*NROWS

__global__ __launch_bounds__(256) void setup_kernel(
    const float* __restrict__ W_x2h, const float* __restrict__ b_x2h,
    const float* __restrict__ W_h2h, const float* __restrict__ b_h2h,
    const float* __restrict__ W_fc2, const float* __restrict__ b_fc2,
    const float* __restrict__ ln_g,  const float* __restrict__ ln_b,
    const float* __restrict__ W_fcsa,const float* __restrict__ b_fcsa,
    const float* __restrict__ W_in,  const float* __restrict__ b_in,
    const float* __restrict__ W_out, const float* __restrict__ b_out,
    float* __restrict__ ws)
{
  int t = blockIdx.x*blockDim.x + threadIdx.x;
  int stride = gridDim.x*blockDim.x;
  for (int i=t;i<1024;i+=stride) ws[OFF_W1+i]   = W_x2h[i];
  for (int i=t;i<1024;i+=stride) ws[OFF_W2+i]   = W_h2h[i];
  for (int i=t;i<3468;i+=stride) ws[OFF_WIN+i]  = W_in[i];
  for (int i=t;i<1024;i+=stride) ws[OFF_WFC2+i] = W_fc2[i];
  for (int i=t;i<32;i+=stride)   ws[OFF_B12+i]  = b_x2h[i] + b_h2h[i];
  for (int i=t;i<102;i+=stride)  ws[OFF_BIN+i]  = b_in[i];
  for (int i=t;i<32;i+=stride)   ws[OFF_BFC2+i] = b_fc2[i];
  for (int i=t;i<32;i+=stride)   ws[OFF_LNG+i]  = ln_g[i];
  for (int i=t;i<32;i+=stride)   ws[OFF_LNB+i]  = ln_b[i];
  // M = W_fcsa (32x34) @ W_out (34x34)
  for (int idx=t; idx<1088; idx+=stride) {
    int j = idx/34, f = idx - j*34;
    float acc = 0.f;
    for (int e=0;e<34;++e)
      acc += W_fcsa[j*34+e] * W_out[e*34+f];
    ws[OFF_M+idx] = acc;
  }
  for (int j=t;j<32;j+=stride){
    float acc = b_fcsa[j];
    for (int e=0;e<34;++e) acc += W_fcsa[j*34+e] * b_out[e];
    ws[OFF_B2+j] = acc;
  }
}

// R10 (best-known 962us) + register v-preload:
// R16 showed the chain is NOT barrier-dominated (removing 3 barriers was
// neutral); the remaining latency term is the softmax phase's 9-18 scattered
// v-loads per lane which serialize AFTER barrier 1 even though their
// addresses are geometry-only. This version issues them into REGISTERS in
// phase A (concurrent with scores + hnew prestage), making the softmax+o
// phase pure LDS/VALU. Everything else is byte-identical to R10.
__global__ __launch_bounds__(TPB) void step_kernel(
    const float* __restrict__ ws,
    const float* __restrict__ qkvR,     // qkv of step stepB (read)
    float* __restrict__ qkvW,           // qkv of step stepA (write)
    float* __restrict__ hnewG,          // feature-major tanh-state
    const float* __restrict__ x,
    float* __restrict__ out,
    int stepB, int stepA)
{
  __shared__ float sW1[32][33], sW2[32][33], sWfc2[32][33];
  __shared__ float sM[32][36];
  __shared__ float sWin[102][36];
  __shared__ float sB12[32], sBin[102], sB2[32], sBfc2[32], sLng[32], sLnb[32];
  __shared__ float sS[RPB][13];      // 9 scores (odd stride: conflict-free)
  __shared__ float sO[RPB][35];      // attention output (34)
  __shared__ float sHp[RPB][33];     // h' (prestaged hnew + attention)
  __shared__ float sG[RPB][33];      // pre-LN fc2 output
  __shared__ float sPred[RPB][33];   // pred (next-step input)
  __shared__ float sHn[RPB][33];     // h_new (tanh output)
  __shared__ float sX[RPB][33];      // staged x chunk (steps 0..9)

  const int tid  = threadIdx.x;
  const int lr2  = tid & 31;         // row within block
  const int slot = tid >> 5;         // work slot 0..31
  const int base = blockIdx.x * RPB;
  const int r2   = base + lr2;
  const int b    = base >> 12;       // batch (uniform)
  const int p    = base & 4095;
  const int gr   = p >> 6;           // grid-row (uniform)
  const int gc0  = p & 63;           // 0 or 32 (uniform)
  const int c    = gc0 + lr2;        // global column (per-lane)
  const int br   = (gr < 1) ? 1 : ((gr > 62) ? 62 : gr);
  const int bc   = (c  < 1) ? 1 : ((c  > 62) ? 62 : c);

  // ---- phase A (no deps, fully concurrent): stage weights/biases + x,
  //      prestage hnew (slots 16..31), scores (slots 0..8),
  //      v-PRELOAD into registers (all slots) ----
  {
    sW1  [tid>>5][tid&31] = ws[OFF_W1  +tid];
    sW2  [tid>>5][tid&31] = ws[OFF_W2  +tid];
    sWfc2[tid>>5][tid&31] = ws[OFF_WFC2+tid];
    for (int idx=tid; idx<1088; idx+=TPB){ int j=idx/34, e=idx-j*34; sM[j][e]=ws[OFF_M+idx]; }
    for (int idx=tid; idx<3468; idx+=TPB){ int e=idx/34, f=idx-e*34; sWin[e][f]=ws[OFF_WIN+idx]; }
    if (tid < 102)                    sBin [tid]     = ws[OFF_BIN +tid];
    else if (tid>=128 && tid<160)     sB12 [tid-128] = ws[OFF_B12 +tid-128];
    else if (tid>=160 && tid<192)     sB2  [tid-160] = ws[OFF_B2  +tid-160];
    else if (tid>=192 && tid<224)     sBfc2[tid-192] = ws[OFF_BFC2+tid-192];
    else if (tid>=224 && tid<256)     sLng [tid-224] = ws[OFF_LNG +tid-224];
    else if (tid>=256 && tid<288)     sLnb [tid-256] = ws[OFF_LNB +tid-256];
  }
  if (stepA >= 0 && stepA < 10) {
    size_t xbase = ((size_t)stepA*NROWS + base)*32;
    sX[tid>>5][tid&31] = x[xbase + tid];           // 1024 floats, coalesced
  }
  float vpre[9], vpre2[9];
  if (stepB >= 0) {
    // v-preload: addresses are geometry-only -> issue now, consume in C.
    // Coalesced per m (rows contiguous across lanes modulo edge clamp).
    const bool e2ok = (slot < 2);                   // half-wave uniform
    #pragma unroll
    for (int m=0;m<9;++m){
      int dr = m/3 - 1, dc = m - (m/3)*3 - 1;
      int nr_ = (b<<12) + ((br+dr)<<6) + (bc+dc);
      vpre[m] = qkvR[(size_t)(68+slot)*NROWS + nr_];
      if (e2ok) vpre2[m] = qkvR[(size_t)(100+slot)*NROWS + nr_];
    }
    if (slot >= 16) {                               // prestage hnew -> sHp
      const int j0 = (slot-16)*2;
      sHp[lr2][j0]   = hnewG[(size_t)j0    *NROWS + r2];
      sHp[lr2][j0+1] = hnewG[(size_t)(j0+1)*NROWS + r2];
    } else if (slot < 9) {                          // scores, m = slot
      const int m  = slot;
      const int dr = m/3 - 1, dc = m - (m/3)*3 - 1;
      const int qrow = (b<<12) + (br<<6) + bc;
      const int nr_  = (b<<12) + ((br+dr)<<6) + (bc+dc);
      float acc = 0.f;
      #pragma unroll
      for (int e=0;e<34;++e)
        acc += qkvR[(size_t)e*NROWS + qrow] * qkvR[(size_t)(34+e)*NROWS + nr_];
      sS[lr2][m] = acc * SCALE;
    }
  } else {
    sHp[lr2][slot] = 0.f;                           // step 0: h' = 0
  }
  __syncthreads();

  if (stepB >= 0) {
    // ---- softmax (redundant per slot) + o from REGISTERS (no global) ----
    {
      float sc[9]; float mx = -1e30f;
      #pragma unroll
      for (int m=0;m<9;++m){ sc[m]=sS[lr2][m]; mx=fmaxf(mx,sc[m]); }
      float sum=0.f;
      #pragma unroll
      for (int m=0;m<9;++m){ sc[m]=__expf(sc[m]-mx); sum+=sc[m]; }
      float inv = 1.f/sum;
      float o0=0.f, o1=0.f;
      const bool e2ok = (slot < 2);
      #pragma unroll
      for (int m=0;m<9;++m){
        float wm = sc[m]*inv;
        o0 += wm * vpre[m];
        if (e2ok) o1 += wm * vpre2[m];
      }
      sO[lr2][slot] = o0;
      if (e2ok) sO[lr2][32+slot] = o1;
    }
    __syncthreads();
    // ---- h' = hnew(prestaged) + o @ M^T + b2 : slot -> j = slot ----
    {
      float a = sB2[slot];
      #pragma unroll
      for (int e=0;e<34;++e) a += sO[lr2][e] * sM[slot][e];
      sHp[lr2][slot] += a;
    }
    __syncthreads();
    // ---- g = h' @ Wfc2^T + b ----
    {
      float g = sBfc2[slot];
      #pragma unroll
      for (int i=0;i<32;++i) g += sHp[lr2][i] * sWfc2[slot][i];
      sG[lr2][slot] = g;
    }
    __syncthreads();
    // ---- layernorm -> sPred ----
    {
      float mu=0.f;
      #pragma unroll
      for (int i=0;i<32;++i) mu += sG[lr2][i];
      mu *= 0.03125f;
      float var=0.f;
      #pragma unroll
      for (int i=0;i<32;++i){ float d=sG[lr2][i]-mu; var += d*d; }
      var *= 0.03125f;
      float rs = rsqrtf(var + 1e-5f);
      sPred[lr2][slot] = (sG[lr2][slot]-mu)*rs*sLng[slot] + sLnb[slot];
    }
    __syncthreads();
    // ---- coalesced out write (block chunk = 1024 contiguous floats) ----
    {
      size_t obase = ((size_t)stepB*NROWS + base)*32;
      out[obase + tid] = sPred[tid>>5][tid&31];
    }
  } else {
    __syncthreads(); __syncthreads(); __syncthreads(); __syncthreads();
  }

  if (stepA >= 0) {
    // ---- h_new = tanh(inp@W1^T + h'@W2^T + b) : slot -> j = slot ----
    {
      float a = sB12[slot];
      if (stepA < 10) {
        #pragma unroll
        for (int i=0;i<32;++i)
          a += sX[lr2][i]*sW1[slot][i] + sHp[lr2][i]*sW2[slot][i];
      } else {
        #pragma unroll
        for (int i=0;i<32;++i)
          a += sPred[lr2][i]*sW1[slot][i] + sHp[lr2][i]*sW2[slot][i];
      }
      float t0 = tanhf(a);
      sHn[lr2][slot] = t0;
      hnewG[(size_t)slot*NROWS + r2] = t0;          // coalesced 128B/slot
    }
    __syncthreads();
    // ---- qkv = [h_new, pl] @ W_in^T + b_in : slot -> e = slot + 32k ----
    float hn[32];
    #pragma unroll
    for (int f=0;f<32;++f) hn[f]=sHn[lr2][f];
    const float pl0 = gr*INV64, pl1 = c*INV64;
    #pragma unroll
    for (int k=0;k<4;++k){
      int e = slot + 32*k;
      if (e < 102) {
        float acc = sBin[e];
        #pragma unroll
        for (int f=0;f<32;++f) acc += hn[f]*sWin[e][f];
        acc += pl0*sWin[e][32] + pl1*sWin[e][33];
        qkvW[(size_t)e*NROWS + r2] = acc;           // coalesced 128B/e
      }
    }
  }
}

extern "C" void kernel_launch(void* const* d_in, const int* in_sizes, int n_in,
                              void* d_out, int out_size, void* d_ws, size_t ws_size,
                              hipStream_t stream) {
  const float* x     = (const float*)d_in[0];
  const float* W_x2h = (const float*)d_in[1];
  const float* b_x2h = (const float*)d_in[2];
  const float* W_h2h = (const float*)d_in[3];
  const float* b_h2h = (const float*)d_in[4];
  const float* W_fc2 = (const float*)d_in[5];
  const float* b_fc2 = (const float*)d_in[6];
  const float* ln_g  = (const float*)d_in[7];
  const float* ln_b  = (const float*)d_in[8];
  const float* W_fcsa= (const float*)d_in[9];
  const float* b_fcsa= (const float*)d_in[10];
  const float* W_in  = (const float*)d_in[11];
  const float* b_in  = (const float*)d_in[12];
  const float* W_out = (const float*)d_in[13];
  const float* b_out = (const float*)d_in[14];
  float* ws = (float*)d_ws;
  float* out = (float*)d_out;

  setup_kernel<<<8, 256, 0, stream>>>(W_x2h,b_x2h,W_h2h,b_h2h,W_fc2,b_fc2,ln_g,ln_b,
                                      W_fcsa,b_fcsa,W_in,b_in,W_out,b_out, ws);
  for (int i=0;i<60;++i){
    int stepB = i-1;
    int stepA = (i<=58)? i : -1;
    const float* qR = ws + OFF_QKV0 + (size_t)((i+1)&1)*QKVN;  // qkv of step i-1
    float*       qW = ws + OFF_QKV0 + (size_t)(i&1)*QKVN;      // qkv of step i
    step_kernel<<<NBLK, TPB, 0, stream>>>(ws, qR, qW, ws+OFF_HNEW, x, out, stepB, stepA);
  }
}